// Round 2
// baseline (826.023 us; speedup 1.0000x reference)
//
#include <hip/hip_runtime.h>
#include <hip/hip_bf16.h>
#include <stdint.h>

#define D_IN   2048
#define D_SAE  32768
#define K_NNZ  64

static __device__ __forceinline__ uint16_t bf16_bits(float x) {
  __hip_bfloat16 h = __float2bfloat16(x);
  return *reinterpret_cast<uint16_t*>(&h);
}

// ---------------------------------------------------------------------------
// Phase 1: W (D_IN x D_SAE) fp32 row-major  ->  W_T (D_SAE x D_IN) bf16
// 64x64 tile via LDS. Load phase unchanged from R1 (coalesced float4, ~2-way
// LDS banking). Store phase now writes 16B (8x bf16) per lane: 8 scalar LDS
// reads (bank = (8a+j+s)%32 -> 2-way, free) + pack + one dwordx4 store.
// ---------------------------------------------------------------------------
__global__ __launch_bounds__(256) void transpose_to_bf16(
    const float* __restrict__ W, __hip_bfloat16* __restrict__ WT) {
  __shared__ float tile[64][65];
  const int s0 = blockIdx.x * 64;   // along D_SAE
  const int d0 = blockIdx.y * 64;   // along D_IN
  const int tid = threadIdx.x;

  // Load: rows -> d, cols -> s (contiguous float4 per lane).
  {
    const int c = (tid & 15) * 4;
    const int rbase = tid >> 4;       // 0..15
#pragma unroll
    for (int i = 0; i < 4; ++i) {
      const int rr = rbase + i * 16;  // 0..63
      const float4 v = *reinterpret_cast<const float4*>(
          &W[(size_t)(d0 + rr) * D_SAE + (size_t)(s0 + c)]);
      tile[rr][c + 0] = v.x;
      tile[rr][c + 1] = v.y;
      tile[rr][c + 2] = v.z;
      tile[rr][c + 3] = v.w;
    }
  }
  __syncthreads();

  // Store: lane owns 8 consecutive d at row s -> one 16B store.
  {
    const int a = tid & 7;            // d-chunk (8 d's)
    const int sb = tid >> 3;          // 0..31
#pragma unroll
    for (int it = 0; it < 2; ++it) {
      const int s = sb + it * 32;
      float f[8];
#pragma unroll
      for (int j = 0; j < 8; ++j) f[j] = tile[a * 8 + j][s];
      uint32_t u[4];
#pragma unroll
      for (int jj = 0; jj < 4; ++jj) {
        u[jj] = (uint32_t)bf16_bits(f[2 * jj]) |
                ((uint32_t)bf16_bits(f[2 * jj + 1]) << 16);
      }
      *reinterpret_cast<uint4*>(&WT[(size_t)(s0 + s) * D_IN + d0 + a * 8]) =
          *reinterpret_cast<uint4*>(u);
    }
  }
}

// ---------------------------------------------------------------------------
// Phase 2: slice-partitioned gather with XCD affinity.
// 32 slices of 64 cols; slice footprint = 32768 x 128B = 4 MB = one XCD L2,
// and 128B/row-slice = one full cache line.
// Grid (rowblks*8, y=4): slice = y*8 + (x%8). Round-robin block->XCD means
// slice s lives on XCD s%8; y-major dispatch retires a whole slice (L2-hot)
// before the XCD moves to its next one.
// Block = 256 thr = 4 waves = 4 rows. Lane l: k-group kg=l>>3 (8 k's in
// flight), chunk c=l&7 (8 bf16 = 16B). Wave-load = 8 rows x 128B = 1 KB
// distinct. 3 xor-shuffle rounds fold the k-groups.
// ---------------------------------------------------------------------------
__global__ __launch_bounds__(256) void sae_decode_sliced(
    const int* __restrict__ indices, const float* __restrict__ values,
    const __hip_bfloat16* __restrict__ WT, const float* __restrict__ bias,
    float* __restrict__ out) {
  const int m = blockIdx.x & 7;
  const int rowblk = blockIdx.x >> 3;
  const int s = blockIdx.y * 8 + m;       // slice 0..31
  const int col0 = s * 64;
  const int tid = threadIdx.x;

  __shared__ int   s_idx[4][K_NNZ];
  __shared__ float s_val[4][K_NNZ];

  {  // 256 threads load 4 rows x 64 (idx, val): fully coalesced.
    const int r = tid >> 6, k = tid & 63;
    const int g = (rowblk * 4 + r) * K_NNZ + k;
    s_idx[r][k] = indices[g];
    s_val[r][k] = values[g];
  }
  __syncthreads();
  {  // last-write-wins dedup (reads s_idx, writes s_val -> no race)
    const int r = tid >> 6, k = tid & 63;
    const int my = s_idx[r][k];
    for (int k2 = k + 1; k2 < K_NNZ; ++k2) {
      if (s_idx[r][k2] == my) { s_val[r][k] = 0.0f; break; }
    }
  }
  __syncthreads();

  const int w  = tid >> 6;                // wave -> row
  const int l  = tid & 63;
  const int kg = l >> 3;                  // k-group 0..7
  const int c  = l & 7;                   // 16B chunk 0..7
  const int row = rowblk * 4 + w;

  float acc[8] = {0.f, 0.f, 0.f, 0.f, 0.f, 0.f, 0.f, 0.f};

#pragma unroll
  for (int step = 0; step < 8; ++step) {
    const int k = step * 8 + kg;
    const float v = s_val[w][k];
    const int idx = s_idx[w][k];
    const uint4 wv = *reinterpret_cast<const uint4*>(
        &WT[(size_t)idx * D_IN + col0 + c * 8]);
#pragma unroll
    for (int j = 0; j < 4; ++j) {
      const uint32_t u = (&wv.x)[j];
      const float lo = __uint_as_float(u << 16);
      const float hi = __uint_as_float(u & 0xffff0000u);
      acc[2 * j + 0] = fmaf(v, lo, acc[2 * j + 0]);
      acc[2 * j + 1] = fmaf(v, hi, acc[2 * j + 1]);
    }
  }

  // Fold the 8 k-groups: lanes differ in bits 3..5.
#pragma unroll
  for (int j = 0; j < 8; ++j) {
    acc[j] += __shfl_xor(acc[j], 8, 64);
    acc[j] += __shfl_xor(acc[j], 16, 64);
    acc[j] += __shfl_xor(acc[j], 32, 64);
  }

  if (kg == 0) {  // lanes 0..7 hold the final 64 cols (8 each)
    const int dbase = col0 + c * 8;
    float4 o0, o1;
    const float4 b0 = *reinterpret_cast<const float4*>(&bias[dbase]);
    const float4 b1 = *reinterpret_cast<const float4*>(&bias[dbase + 4]);
    o0.x = acc[0] + b0.x; o0.y = acc[1] + b0.y;
    o0.z = acc[2] + b0.z; o0.w = acc[3] + b0.w;
    o1.x = acc[4] + b1.x; o1.y = acc[5] + b1.y;
    o1.z = acc[6] + b1.z; o1.w = acc[7] + b1.w;
    float4* o = reinterpret_cast<float4*>(&out[(size_t)row * D_IN + dbase]);
    o[0] = o0;
    o[1] = o1;
  }
}

// ---------------------------------------------------------------------------
// Fallback (workspace too small): direct fp32 gather. Insurance only.
// ---------------------------------------------------------------------------
__global__ __launch_bounds__(256) void sae_decode_direct(
    const int* __restrict__ indices, const float* __restrict__ values,
    const float* __restrict__ W, const float* __restrict__ bias,
    float* __restrict__ out) {
  const int row = blockIdx.x;
  const int tid = threadIdx.x;

  __shared__ int   s_idx[K_NNZ];
  __shared__ float s_val[K_NNZ];
  if (tid < K_NNZ) {
    s_idx[tid] = indices[row * K_NNZ + tid];
    s_val[tid] = values[row * K_NNZ + tid];
  }
  __syncthreads();
  if (tid < K_NNZ) {
    const int my = s_idx[tid];
    for (int k2 = tid + 1; k2 < K_NNZ; ++k2) {
      if (s_idx[k2] == my) { s_val[tid] = 0.0f; break; }
    }
  }
  __syncthreads();

  const int d0 = tid * 8;
  float acc[8];
#pragma unroll
  for (int j = 0; j < 8; ++j) acc[j] = bias[d0 + j];

  for (int k = 0; k < K_NNZ; ++k) {
    const float v = s_val[k];
    const int idx = s_idx[k];
#pragma unroll
    for (int j = 0; j < 8; ++j) {
      acc[j] = fmaf(v, W[(size_t)(d0 + j) * D_SAE + idx], acc[j]);
    }
  }
  float4* o = reinterpret_cast<float4*>(&out[(size_t)row * D_IN + d0]);
  o[0] = make_float4(acc[0], acc[1], acc[2], acc[3]);
  o[1] = make_float4(acc[4], acc[5], acc[6], acc[7]);
}

extern "C" void kernel_launch(void* const* d_in, const int* in_sizes, int n_in,
                              void* d_out, int out_size, void* d_ws, size_t ws_size,
                              hipStream_t stream) {
  const int*   indices = (const int*)d_in[0];
  const float* values  = (const float*)d_in[1];
  const float* W       = (const float*)d_in[2];
  const float* bias    = (const float*)d_in[3];
  float* out = (float*)d_out;

  const int n_rows = in_sizes[0] / K_NNZ;  // 8192
  const size_t wt_bytes = (size_t)D_SAE * D_IN * sizeof(__hip_bfloat16);  // 128 MB

  if (ws_size >= wt_bytes && (n_rows & 3) == 0) {
    __hip_bfloat16* WT = (__hip_bfloat16*)d_ws;
    dim3 g1(D_SAE / 64, D_IN / 64);  // 512 x 32
    transpose_to_bf16<<<g1, 256, 0, stream>>>(W, WT);
    dim3 g2((n_rows / 4) * 8, 4);    // x: rowblk*8+m, y: slice group
    sae_decode_sliced<<<g2, 256, 0, stream>>>(indices, values, WT, bias, out);
  } else {
    sae_decode_direct<<<n_rows, 256, 0, stream>>>(indices, values, W, bias, out);
  }
}

// Round 4
// 619.060 us; speedup vs baseline: 1.3343x; 1.3343x over previous
//
#include <hip/hip_runtime.h>
#include <hip/hip_bf16.h>
#include <stdint.h>

#define D_IN   2048
#define D_SAE  32768
#define K_NNZ  64

typedef float vfloat4 __attribute__((ext_vector_type(4)));  // native vec for nontemporal

static __device__ __forceinline__ uint16_t bf16_bits(float x) {
  __hip_bfloat16 h = __float2bfloat16(x);
  return *reinterpret_cast<uint16_t*>(&h);
}

// ---------------------------------------------------------------------------
// Dedup precompute: scatter .set = last-write-wins. v_clean[r][k] = 0 if any
// k' > k shares idx. One wave per row; runs once, removes dedup from the
// slice loop entirely.
// ---------------------------------------------------------------------------
__global__ __launch_bounds__(64) void dedup_values(
    const int* __restrict__ indices, const float* __restrict__ values,
    float* __restrict__ v_clean) {
  __shared__ int si[K_NNZ];
  const int r = blockIdx.x;
  const int k = threadIdx.x;
  const int my = indices[(size_t)r * K_NNZ + k];
  si[k] = my;
  __syncthreads();
  float v = values[(size_t)r * K_NNZ + k];
  for (int k2 = k + 1; k2 < K_NNZ; ++k2) {
    if (si[k2] == my) { v = 0.0f; break; }
  }
  v_clean[(size_t)r * K_NNZ + k] = v;
}

// ---------------------------------------------------------------------------
// Transpose v2: W (2048 x 32768) fp32 -> WT (32768 x 2048) bf16.
// Tile 64(d) x 256(s): reads are full 1KB contiguous spans per W row
// (vs 256B in v1 -> 4x longer HBM bursts per 128KB-strided row), writes are
// full 128B lines of WT. LDS: 64KB fp32 tile, XOR-swizzled chunk layout
// (p = chunk ^ ((r>>3)&7), pitch 256) -> phase-A b128 writes capacity-
// optimal, phase-B scalar reads <=2-way banked.
// ---------------------------------------------------------------------------
#define TP_D 64
#define TP_S 256

static __device__ __forceinline__ int sw_idx(int r, int c) {
  return (((c >> 2) ^ ((r >> 3) & 7)) << 2) + (c & 3);
}

__global__ __launch_bounds__(256) void transpose_to_bf16_v2(
    const float* __restrict__ W, __hip_bfloat16* __restrict__ WT) {
  __shared__ float tile[TP_D][TP_S];
  const int s0 = blockIdx.x * TP_S;
  const int d0 = blockIdx.y * TP_D;
  const int tid = threadIdx.x;
  const int w = tid >> 6, l = tid & 63;

  // Phase A: wave w loads rows w*16..w*16+15; per row one 1KB wave-load.
#pragma unroll
  for (int i = 0; i < 16; ++i) {
    const int r = w * 16 + i;
    const float4 v = *reinterpret_cast<const float4*>(
        &W[(size_t)(d0 + r) * D_SAE + s0 + l * 4]);
    const int p = l ^ ((r >> 3) & 7);   // chunk swizzle
    *reinterpret_cast<float4*>(&tile[r][p << 2]) = v;
  }
  __syncthreads();

  // Phase B: wave w covers s_local [w*64, w*64+64); lane: a=d-chunk, sub=s.
  const int a = l & 7;
  const int sub = l >> 3;
#pragma unroll
  for (int i = 0; i < 8; ++i) {
    const int sl = w * 64 + i * 8 + sub;
    uint32_t u[4];
#pragma unroll
    for (int jj = 0; jj < 4; ++jj) {
      const float f0 = tile[a * 8 + 2 * jj][sw_idx(a * 8 + 2 * jj, sl)];
      const float f1 = tile[a * 8 + 2 * jj + 1][sw_idx(a * 8 + 2 * jj + 1, sl)];
      u[jj] = (uint32_t)bf16_bits(f0) | ((uint32_t)bf16_bits(f1) << 16);
    }
    *reinterpret_cast<uint4*>(&WT[(size_t)(s0 + sl) * D_IN + d0 + a * 8]) =
        *reinterpret_cast<uint4*>(u);
  }
}

// ---------------------------------------------------------------------------
// Decode v3: L2-resident slices + row-chunk amortization.
// slice = 64 cols = 4MB of WT = one XCD L2, pinned via blockIdx.x%8;
// y = phase (4 slices per XCD, sequential in dispatch order).
// Block = 256 thr, 64 rows x 1 slice: stage 64x64 idx/val in LDS (32KB),
// then wave w processes rows w,w+4,... Per row: 8 gather instrs (kg=l>>3
// picks k, c=l&7 picks 16B chunk), 3 xor-shuffle folds, one 2xfloat4 store.
// Setup cost amortized over 64 rows; 16 independent row-iterations per wave
// keep ~8 loads in flight. Out stores nontemporal (protect WT in L2).
// ---------------------------------------------------------------------------
__global__ __launch_bounds__(256) void sae_decode_l2(
    const int* __restrict__ indices, const float* __restrict__ v_clean,
    const __hip_bfloat16* __restrict__ WT, const float* __restrict__ bias,
    float* __restrict__ out) {
  const int m = blockIdx.x & 7;
  const int rowchunk = blockIdx.x >> 3;
  const int slice = blockIdx.y * 8 + m;        // 0..31, XCD = slice%8
  const int col0 = slice * 64;
  const int r0 = rowchunk * 64;
  const int tid = threadIdx.x;
  const int w = tid >> 6, l = tid & 63;

  __shared__ int   s_idx[64 * K_NNZ];
  __shared__ float s_val[64 * K_NNZ];

  {  // stage 64 rows of (idx, v_clean): 4096 elems each, int4/float4 loads
    const int4*   gi = reinterpret_cast<const int4*>(&indices[(size_t)r0 * K_NNZ]);
    const float4* gv = reinterpret_cast<const float4*>(&v_clean[(size_t)r0 * K_NNZ]);
#pragma unroll
    for (int i = 0; i < 4; ++i) {
      const int e = i * 256 + tid;
      reinterpret_cast<int4*>(s_idx)[e] = gi[e];
      reinterpret_cast<float4*>(s_val)[e] = gv[e];
    }
  }
  __syncthreads();

  const int kg = l >> 3;                 // k-group 0..7
  const int c  = l & 7;                  // 16B chunk 0..7
  const __hip_bfloat16* wbase = WT + col0 + c * 8;

  for (int i = 0; i < 16; ++i) {
    const int r = w + 4 * i;
    float acc[8] = {0.f, 0.f, 0.f, 0.f, 0.f, 0.f, 0.f, 0.f};
#pragma unroll
    for (int step = 0; step < 8; ++step) {
      const int k = step * 8 + kg;
      const int idx = s_idx[r * K_NNZ + k];   // broadcast across c -> no conflict
      const float v = s_val[r * K_NNZ + k];
      const uint4 wv = *reinterpret_cast<const uint4*>(&wbase[(size_t)idx * D_IN]);
#pragma unroll
      for (int j = 0; j < 4; ++j) {
        const uint32_t u = (&wv.x)[j];
        const float lo = __uint_as_float(u << 16);
        const float hi = __uint_as_float(u & 0xffff0000u);
        acc[2 * j + 0] = fmaf(v, lo, acc[2 * j + 0]);
        acc[2 * j + 1] = fmaf(v, hi, acc[2 * j + 1]);
      }
    }
#pragma unroll
    for (int j = 0; j < 8; ++j) {
      acc[j] += __shfl_xor(acc[j], 8, 64);
      acc[j] += __shfl_xor(acc[j], 16, 64);
      acc[j] += __shfl_xor(acc[j], 32, 64);
    }
    if (kg == 0) {
      const int dbase = col0 + c * 8;
      const float4 b0 = *reinterpret_cast<const float4*>(&bias[dbase]);
      const float4 b1 = *reinterpret_cast<const float4*>(&bias[dbase + 4]);
      vfloat4 o0 = {acc[0] + b0.x, acc[1] + b0.y, acc[2] + b0.z, acc[3] + b0.w};
      vfloat4 o1 = {acc[4] + b1.x, acc[5] + b1.y, acc[6] + b1.z, acc[7] + b1.w};
      vfloat4* o = reinterpret_cast<vfloat4*>(&out[(size_t)(r0 + r) * D_IN + dbase]);
      __builtin_nontemporal_store(o0, &o[0]);
      __builtin_nontemporal_store(o1, &o[1]);
    }
  }
}

// ---------------------------------------------------------------------------
// Fallback A (ws fits WT but not v_clean): R1's proven decode (in-kernel
// dedup, full-row blocks, 314 us).
// ---------------------------------------------------------------------------
__global__ __launch_bounds__(256) void sae_decode_r1(
    const int* __restrict__ indices, const float* __restrict__ values,
    const __hip_bfloat16* __restrict__ WT, const float* __restrict__ bias,
    float* __restrict__ out) {
  const int row = blockIdx.x;
  const int tid = threadIdx.x;

  __shared__ int   s_idx[K_NNZ];
  __shared__ float s_val[K_NNZ];
  if (tid < K_NNZ) {
    s_idx[tid] = indices[(size_t)row * K_NNZ + tid];
    s_val[tid] = values[(size_t)row * K_NNZ + tid];
  }
  __syncthreads();
  if (tid < K_NNZ) {
    const int my = s_idx[tid];
    for (int k2 = tid + 1; k2 < K_NNZ; ++k2) {
      if (s_idx[k2] == my) { s_val[tid] = 0.0f; break; }
    }
  }
  __syncthreads();

  const int d0 = tid * 8;
  float acc[8];
  {
    const float4 b0 = *reinterpret_cast<const float4*>(&bias[d0]);
    const float4 b1 = *reinterpret_cast<const float4*>(&bias[d0 + 4]);
    acc[0] = b0.x; acc[1] = b0.y; acc[2] = b0.z; acc[3] = b0.w;
    acc[4] = b1.x; acc[5] = b1.y; acc[6] = b1.z; acc[7] = b1.w;
  }
#pragma unroll 4
  for (int k = 0; k < K_NNZ; ++k) {
    const float v = s_val[k];
    const int idx = s_idx[k];
    const uint4 wv = *reinterpret_cast<const uint4*>(
        &WT[(size_t)idx * D_IN + d0]);
#pragma unroll
    for (int j = 0; j < 4; ++j) {
      const uint32_t u = (&wv.x)[j];
      const float lo = __uint_as_float(u << 16);
      const float hi = __uint_as_float(u & 0xffff0000u);
      acc[2 * j + 0] = fmaf(v, lo, acc[2 * j + 0]);
      acc[2 * j + 1] = fmaf(v, hi, acc[2 * j + 1]);
    }
  }
  float4* o = reinterpret_cast<float4*>(&out[(size_t)row * D_IN + d0]);
  o[0] = make_float4(acc[0], acc[1], acc[2], acc[3]);
  o[1] = make_float4(acc[4], acc[5], acc[6], acc[7]);
}

// ---------------------------------------------------------------------------
// Fallback B (tiny ws): direct fp32 gather. Insurance only.
// ---------------------------------------------------------------------------
__global__ __launch_bounds__(256) void sae_decode_direct(
    const int* __restrict__ indices, const float* __restrict__ values,
    const float* __restrict__ W, const float* __restrict__ bias,
    float* __restrict__ out) {
  const int row = blockIdx.x;
  const int tid = threadIdx.x;
  __shared__ int   s_idx[K_NNZ];
  __shared__ float s_val[K_NNZ];
  if (tid < K_NNZ) {
    s_idx[tid] = indices[(size_t)row * K_NNZ + tid];
    s_val[tid] = values[(size_t)row * K_NNZ + tid];
  }
  __syncthreads();
  if (tid < K_NNZ) {
    const int my = s_idx[tid];
    for (int k2 = tid + 1; k2 < K_NNZ; ++k2) {
      if (s_idx[k2] == my) { s_val[tid] = 0.0f; break; }
    }
  }
  __syncthreads();
  const int d0 = tid * 8;
  float acc[8];
#pragma unroll
  for (int j = 0; j < 8; ++j) acc[j] = bias[d0 + j];
  for (int k = 0; k < K_NNZ; ++k) {
    const float v = s_val[k];
    const int idx = s_idx[k];
#pragma unroll
    for (int j = 0; j < 8; ++j) {
      acc[j] = fmaf(v, W[(size_t)(d0 + j) * D_SAE + idx], acc[j]);
    }
  }
  float4* o = reinterpret_cast<float4*>(&out[(size_t)row * D_IN + d0]);
  o[0] = make_float4(acc[0], acc[1], acc[2], acc[3]);
  o[1] = make_float4(acc[4], acc[5], acc[6], acc[7]);
}

extern "C" void kernel_launch(void* const* d_in, const int* in_sizes, int n_in,
                              void* d_out, int out_size, void* d_ws, size_t ws_size,
                              hipStream_t stream) {
  const int*   indices = (const int*)d_in[0];
  const float* values  = (const float*)d_in[1];
  const float* W       = (const float*)d_in[2];
  const float* bias    = (const float*)d_in[3];
  float* out = (float*)d_out;

  const int n_rows = in_sizes[0] / K_NNZ;  // 8192
  const size_t wt_bytes = (size_t)D_SAE * D_IN * sizeof(__hip_bfloat16);
  const size_t vc_bytes = (size_t)n_rows * K_NNZ * sizeof(float);

  if (ws_size >= wt_bytes + vc_bytes && (n_rows % 64) == 0) {
    __hip_bfloat16* WT = (__hip_bfloat16*)d_ws;
    float* v_clean = (float*)((char*)d_ws + wt_bytes);
    transpose_to_bf16_v2<<<dim3(D_SAE / TP_S, D_IN / TP_D), 256, 0, stream>>>(W, WT);
    dedup_values<<<n_rows, 64, 0, stream>>>(indices, values, v_clean);
    dim3 g2(8 * (n_rows / 64), 4);  // x: rowchunk*8+xcd, y: phase
    sae_decode_l2<<<g2, 256, 0, stream>>>(indices, v_clean, WT, bias, out);
  } else if (ws_size >= wt_bytes) {
    __hip_bfloat16* WT = (__hip_bfloat16*)d_ws;
    transpose_to_bf16_v2<<<dim3(D_SAE / TP_S, D_IN / TP_D), 256, 0, stream>>>(W, WT);
    sae_decode_r1<<<n_rows, 256, 0, stream>>>(indices, values, WT, bias, out);
  } else {
    sae_decode_direct<<<n_rows, 256, 0, stream>>>(indices, values, W, bias, out);
  }
}